// Round 12
// baseline (1371.949 us; speedup 1.0000x reference)
//
#include <hip/hip_runtime.h>

typedef unsigned short u16;
typedef unsigned int u32;
typedef unsigned long long u64;
typedef __attribute__((ext_vector_type(8))) short bf16x8;
typedef __attribute__((ext_vector_type(4))) float f32x4;
typedef __attribute__((ext_vector_type(4))) float fvec4;

#define Tn 512
#define Bn 256
#define Hn 512
#define SLOTS 32
#define SLABB 16384      // 16KB slab: [16 waves][4 kseg][16 col][16B]
#define NSLAB 192        // (kk*6+g)*2+half
#define RING 5           // 80KB LDS ring; slab p+5 issued at phase p -> 4-phase landing budget

__device__ __forceinline__ u16 f2bf(float x){
  u32 u = __builtin_bit_cast(u32, x);
  u32 r = u + 0x7FFFu + ((u >> 16) & 1u);
  return (u16)(r >> 16);
}
__device__ __forceinline__ float bf2f(u16 x){
  return __builtin_bit_cast(float, ((u32)x) << 16);
}
__device__ __forceinline__ float sigmoid_f(float x){ return 1.0f/(1.0f + __expf(-x)); }
__device__ __forceinline__ float tanh_f(float x){ return 2.0f/(1.0f + __expf(-2.0f*x)) - 1.0f; }

__device__ __forceinline__ void dma16(const void* g, void* l) {
  __builtin_amdgcn_global_load_lds(
      (const __attribute__((address_space(1))) unsigned int*)g,
      (__attribute__((address_space(3))) unsigned int*)l,
      16, 0, 0);
}

// A-frag read from swizzled x/h LDS
__device__ __forceinline__ bf16x8 ldsA(const u16* buf, int m, int kk, int lane) {
  const int row = (m << 4) + (lane & 15);
  const int ke  = (kk << 5) + ((lane >> 4) << 3);
  const int byt = (row << 10) + ((ke << 1) ^ ((row & 7) << 4));
  return *(const bf16x8*)((const char*)buf + byt);
}

// Pack weights into slab order (R6's verified layout).
// Slab s = (kk*6+g)*2+half; within slab: e = wv*512 + kseg*128 + c*8 + j
//   = W_g[(kk*32 + kseg*8 + j)*512 + half*256 + wv*16 + c]
__global__ __launch_bounds__(256) void prep_w(
    const float* __restrict__ Wir, const float* __restrict__ Wiz, const float* __restrict__ Win,
    const float* __restrict__ Whr, const float* __restrict__ Whz, const float* __restrict__ Whn,
    u16* __restrict__ wt)
{
  int idx = blockIdx.x * 256 + threadIdx.x;   // 0 .. 6*512*512-1
  int within = idx & 8191;
  int slab = idx >> 13;
  int wv   = within >> 9;
  int r2   = within & 511;
  int kseg = r2 >> 7;
  int c    = (r2 >> 3) & 15;
  int j    = r2 & 7;
  int half = slab & 1;
  int gk = slab >> 1;
  int g  = gk % 6;
  int kk = gk / 6;
  int k = (kk << 5) + (kseg << 3) + j;
  int n = (half << 8) + (wv << 4) + c;
  const float* W;
  switch (g) {
    case 0: W = Wir; break; case 1: W = Wiz; break; case 2: W = Win; break;
    case 3: W = Whr; break; case 4: W = Whz; break; default: W = Whn; break;
  }
  wt[idx] = f2bf(W[k * Hn + n]);
}

// Per-phase body: read B slab from ring, 2 MFMAs into the right gate acc,
// drain own ds_reads, then DMA the slab 5 ahead into the same buf, vmcnt(4).
#define PHASE_BODY(AXH0, AXH1, ACC, HALF, ISSUE, TAILW)                              \
  do {                                                                               \
    bf16x8 bb = *(const bf16x8*)(wring + bufoff + brd_off);                          \
    ACC[HALF][0] = __builtin_amdgcn_mfma_f32_16x16x32_bf16(AXH0, bb, ACC[HALF][0], 0, 0, 0); \
    ACC[HALF][1] = __builtin_amdgcn_mfma_f32_16x16x32_bf16(AXH1, bb, ACC[HALF][1], 0, 0, 0); \
    asm volatile("s_waitcnt lgkmcnt(0)" ::: "memory");                               \
    __builtin_amdgcn_sched_barrier(0);                                               \
    if (ISSUE) {                                                                     \
      dma16(pf, wring + bufoff + lds_wave_off);                                      \
      pf += SLABB;                                                                   \
      asm volatile("s_waitcnt vmcnt(4)" ::: "memory");                               \
    } else if (TAILW == 3) { asm volatile("s_waitcnt vmcnt(3)" ::: "memory");        \
    } else if (TAILW == 2) { asm volatile("s_waitcnt vmcnt(2)" ::: "memory");        \
    } else if (TAILW == 1) { asm volatile("s_waitcnt vmcnt(1)" ::: "memory");        \
    } else if (TAILW == 0) { asm volatile("s_waitcnt vmcnt(0)" ::: "memory"); }      \
    __builtin_amdgcn_sched_barrier(0);                                               \
    bufoff = (bufoff == 4 * SLABB) ? 0 : bufoff + SLABB;                             \
  } while (0)

// One WG (1024 thr, 16 waves) per batch row; R6 structure with a 5-slab
// wave-private LDS ring, single-slab phases, ROLLED kk loop (runtime bufoff;
// R10's full unroll was what spilled). Slab stream pointer advances linearly.
__global__ __launch_bounds__(1024, 4) void gru_chains(
    const float* __restrict__ ins,      // [T,B,H] fp32
    const int*   __restrict__ resets,   // [T,B] int32 0/1
    const u16*   __restrict__ wt,       // [192] slabs of 16KB
    const float* __restrict__ bir, const float* __restrict__ biz,
    const float* __restrict__ bin_, const float* __restrict__ bhn,
    float* __restrict__ out)            // [T,B,H] fp32
{
  __shared__ __attribute__((aligned(16))) u16 x_lds[SLOTS * 512];    // 32KB swizzled
  __shared__ __attribute__((aligned(16))) u16 h_lds[SLOTS * 512];    // 32KB swizzled
  __shared__ __attribute__((aligned(16))) char wring[RING * SLABB];  // 80KB ring
  __shared__ u32 keys[512];
  __shared__ int slot_t[SLOTS];
  __shared__ int slot_end[SLOTS];
  __shared__ int slot_active[SLOTS];
  __shared__ int slot_fresh[SLOTS];
  __shared__ int wave_cnt[16];
  __shared__ int queue_head, n_chains, n_active;

  const int tid  = threadIdx.x;
  const int b    = blockIdx.x;
  const int wv   = tid >> 6;
  const int lane = tid & 63;

  // ---------------- chain extraction + LPT sort ----------------
  {
    u32* starts_tmp = (u32*)wring;   // wring unused during setup
    int t = tid;
    int isst = 0;
    if (t < Tn) isst = (t == 0) || (resets[t * Bn + b] != 0);
    u64 mask = __ballot(isst);
    int pos = __popcll(mask & ((1ull << lane) - 1ull));
    if (lane == 0) wave_cnt[wv] = __popcll(mask);
    __syncthreads();
    if (tid == 0) {
      int s = 0;
      for (int w = 0; w < 16; ++w) { int c = wave_cnt[w]; wave_cnt[w] = s; s += c; }
      n_chains = s;
      queue_head = SLOTS;
    }
    __syncthreads();
    if (isst) starts_tmp[wave_cnt[wv] + pos] = (u32)t;
    __syncthreads();
    const int nc = n_chains;
    if (tid < 512) {
      int i = tid;
      u32 key = 0;
      if (i < nc) {
        u32 st = starts_tmp[i];
        u32 en = (i + 1 < nc) ? starts_tmp[i + 1] : (u32)Tn;
        key = ((en - st) << 16) | st;
      }
      keys[i] = key;
    }
    for (int ks = 2; ks <= 512; ks <<= 1) {
      for (int j = ks >> 1; j > 0; j >>= 1) {
        __syncthreads();
        if (tid < 512) {
          int i = tid;
          int ix = i ^ j;
          if (ix > i) {
            u32 a = keys[i], c = keys[ix];
            bool desc = ((i & ks) == 0);
            bool sw = desc ? (a < c) : (a > c);
            if (sw) { keys[i] = c; keys[ix] = a; }
          }
        }
      }
    }
    __syncthreads();
    if (tid < SLOTS) {
      if (tid < nc) {
        u32 key = keys[tid];
        slot_t[tid]   = (int)(key & 0xFFFFu);
        slot_end[tid] = (int)((key & 0xFFFFu) + (key >> 16));
        slot_active[tid] = 1;
      } else {
        slot_active[tid] = 0; slot_t[tid] = 0; slot_end[tid] = 0;
      }
      slot_fresh[tid] = 0;
    }
    if (tid == 0) n_active = (nc < SLOTS) ? nc : SLOTS;
    for (int i = tid; i < SLOTS * 512 / 2; i += 1024) ((u32*)h_lds)[i] = 0;
    __syncthreads();
  }

  // ---- initial x stage: 2048 granules of 8 bf16, 2 per thread ----
  #pragma unroll
  for (int i = 0; i < 2; ++i) {
    const int g   = tid + (i << 10);
    const int row = g >> 6;
    const int k0  = (g & 63) << 3;
    const int act = slot_active[row];
    const int tc  = slot_t[row];
    fvec4 f0 = (fvec4){0.f, 0.f, 0.f, 0.f}, f1 = f0;
    if (act) {
      const fvec4* src = (const fvec4*)(ins + ((size_t)tc * Bn + b) * Hn + k0);
      f0 = __builtin_nontemporal_load(src);
      f1 = __builtin_nontemporal_load(src + 1);
    }
    uint4 pk;
    pk.x = (u32)f2bf(f0.x) | ((u32)f2bf(f0.y) << 16);
    pk.y = (u32)f2bf(f0.z) | ((u32)f2bf(f0.w) << 16);
    pk.z = (u32)f2bf(f1.x) | ((u32)f2bf(f1.y) << 16);
    pk.w = (u32)f2bf(f1.z) | ((u32)f2bf(f1.w) << 16);
    const int byt = (row << 10) + ((k0 << 1) ^ ((row & 7) << 4));
    *(uint4*)((char*)x_lds + byt) = pk;
  }
  __syncthreads();   // drains all counters; per-wave vmcnt bookkeeping clean

  // bias registers
  const int colw = (wv << 4) + (lane & 15);            // col within 256-half
  float b_r[2], b_z[2], b_n[2], b_h[2];
  #pragma unroll
  for (int half = 0; half < 2; ++half) {
    const int col = (half << 8) + colw;
    b_r[half] = bir[col]; b_z[half] = biz[col]; b_n[half] = bin_[col]; b_h[half] = bhn[col];
  }

  const u32 dm_lane_off  = (u32)((wv << 10) + (lane << 4));  // per-lane src off in slab
  const u32 lds_wave_off = (u32)(wv << 10);                  // wave-uniform LDS dest slice
  const int brd_off      = (wv << 10) + ((lane >> 4) << 8) + ((lane & 15) << 4);

  // ---------------- microstep loop ----------------
  for (;;) {
    f32x4 accR[2][2], accZ[2][2], accXN[2][2], accHN[2][2];   // [half][mfrag]
    #pragma unroll
    for (int hh = 0; hh < 2; ++hh)
      #pragma unroll
      for (int m = 0; m < 2; ++m) {
        accR[hh][m] = (f32x4){0.f, 0.f, 0.f, 0.f};
        accZ[hh][m] = accR[hh][m]; accXN[hh][m] = accR[hh][m]; accHN[hh][m] = accR[hh][m];
      }

    // prologue: issue slabs 0..4, wait slab0 (4 newest still pending)
    const char* pf = (const char*)wt + dm_lane_off;
    {
      #pragma unroll
      for (int s = 0; s < RING; ++s) {
        dma16(pf, wring + s * SLABB + lds_wave_off);
        pf += SLABB;
      }
      asm volatile("s_waitcnt vmcnt(4)" ::: "memory");
      __builtin_amdgcn_sched_barrier(0);
    }

    u32 bufoff = 0;
    // kk = 0..14 rolled (all issue slab p+5, vmcnt(4)); kk = 15 peeled (tail)
    for (int kk = 0; kk < 15; ++kk) {
      bf16x8 ax0, ax1, ah0, ah1;
      #pragma unroll
      for (int g = 0; g < 6; ++g) {
        if (g == 0) { ax0 = ldsA(x_lds, 0, kk, lane); ax1 = ldsA(x_lds, 1, kk, lane); }
        if (g == 3) { ah0 = ldsA(h_lds, 0, kk, lane); ah1 = ldsA(h_lds, 1, kk, lane); }
        bf16x8 a0 = (g < 3) ? ax0 : ah0;
        bf16x8 a1 = (g < 3) ? ax1 : ah1;
        #pragma unroll
        for (int half = 0; half < 2; ++half) {
          if (g == 0 || g == 3)      PHASE_BODY(a0, a1, accR,  half, 1, -1);
          else if (g == 1 || g == 4) PHASE_BODY(a0, a1, accZ,  half, 1, -1);
          else if (g == 2)           PHASE_BODY(a0, a1, accXN, half, 1, -1);
          else                       PHASE_BODY(a0, a1, accHN, half, 1, -1);
        }
      }
    }
    // kk = 15 peeled: phases 180..191; issue while p+5<192 (p<=186), then tail waits
    {
      const int kk = 15;
      bf16x8 ax0, ax1, ah0, ah1;
      #pragma unroll
      for (int g = 0; g < 6; ++g) {
        if (g == 0) { ax0 = ldsA(x_lds, 0, kk, lane); ax1 = ldsA(x_lds, 1, kk, lane); }
        if (g == 3) { ah0 = ldsA(h_lds, 0, kk, lane); ah1 = ldsA(h_lds, 1, kk, lane); }
        bf16x8 a0 = (g < 3) ? ax0 : ah0;
        bf16x8 a1 = (g < 3) ? ax1 : ah1;
        #pragma unroll
        for (int half = 0; half < 2; ++half) {
          const int p = 180 + g * 2 + half;
          const int issue = (p <= 186) ? 1 : 0;
          const int tailw = (p >= 187 && p <= 190) ? (190 - p) : -1;  // 3,2,1,0
          if (g == 0 || g == 3)      PHASE_BODY(a0, a1, accR,  half, issue, tailw);
          else if (g == 1 || g == 4) PHASE_BODY(a0, a1, accZ,  half, issue, tailw);
          else if (g == 2)           PHASE_BODY(a0, a1, accXN, half, issue, tailw);
          else                       PHASE_BODY(a0, a1, accHN, half, issue, tailw);
        }
      }
    }

    __syncthreads();   // all waves done reading x_lds/h_lds

    // ---- epilogue: gates, h update (in place), y store ----
    #pragma unroll
    for (int half = 0; half < 2; ++half) {
      const int col = (half << 8) + colw;
      const float bi_r = b_r[half], bi_z = b_z[half], bi_n = b_n[half], bh_n = b_h[half];
      #pragma unroll
      for (int m = 0; m < 2; ++m) {
        #pragma unroll
        for (int i = 0; i < 4; ++i) {
          const int slot = (m << 4) + ((lane >> 4) << 2) + i;
          float rr = sigmoid_f(accR[half][m][i] + bi_r);
          float zz = sigmoid_f(accZ[half][m][i] + bi_z);
          const int hbyt = (slot << 10) + ((col << 1) ^ ((slot & 7) << 4));
          float hold = bf2f(*(const u16*)((const char*)h_lds + hbyt));
          float nn = tanh_f(accXN[half][m][i] + bi_n + rr * (accHN[half][m][i] + bh_n));
          float hnew = (1.0f - zz) * nn + zz * hold;
          *(u16*)((char*)h_lds + hbyt) = f2bf(hnew);   // (slot,col) owned by this thread
          if (slot_active[slot]) {
            __builtin_nontemporal_store(hnew, out + ((size_t)slot_t[slot] * Bn + b) * Hn + col);
          }
        }
      }
    }
    __syncthreads();

    // ---- advance slots / repack from queue ----
    if (tid < SLOTS) {
      const int s = tid;
      int fresh = 0;
      if (slot_active[s]) {
        int nt = slot_t[s] + 1;
        if (nt >= slot_end[s]) {
          int idx = atomicAdd(&queue_head, 1);
          if (idx < n_chains) {
            u32 key = keys[idx];
            slot_t[s]   = (int)(key & 0xFFFFu);
            slot_end[s] = (int)((key & 0xFFFFu) + (key >> 16));
            fresh = 1;
          } else {
            slot_active[s] = 0;
            atomicSub(&n_active, 1);
            fresh = 1;
          }
        } else {
          slot_t[s] = nt;
        }
      }
      slot_fresh[s] = fresh;
    }
    __syncthreads();

    // ---- stage next x + zero h rows of fresh/inactive slots ----
    #pragma unroll
    for (int i = 0; i < 2; ++i) {
      const int g   = tid + (i << 10);
      const int row = g >> 6;
      const int k0  = (g & 63) << 3;
      const int act = slot_active[row];
      const int tc  = slot_t[row];
      const int kill = slot_fresh[row] | (act == 0);
      const int sbyt = (row << 10) + ((k0 << 1) ^ ((row & 7) << 4));
      if (kill) *(uint4*)((char*)h_lds + sbyt) = (uint4){0, 0, 0, 0};
      fvec4 f0 = (fvec4){0.f, 0.f, 0.f, 0.f}, f1 = f0;
      if (act) {
        const fvec4* src = (const fvec4*)(ins + ((size_t)tc * Bn + b) * Hn + k0);
        f0 = __builtin_nontemporal_load(src);
        f1 = __builtin_nontemporal_load(src + 1);
      }
      uint4 pk;
      pk.x = (u32)f2bf(f0.x) | ((u32)f2bf(f0.y) << 16);
      pk.y = (u32)f2bf(f0.z) | ((u32)f2bf(f0.w) << 16);
      pk.z = (u32)f2bf(f1.x) | ((u32)f2bf(f1.y) << 16);
      pk.w = (u32)f2bf(f1.z) | ((u32)f2bf(f1.w) << 16);
      *(uint4*)((char*)x_lds + sbyt) = pk;
    }
    __syncthreads();    // drains all vmem counters before next prologue

    if (n_active <= 0) break;
  }
}

extern "C" void kernel_launch(void* const* d_in, const int* in_sizes, int n_in,
                              void* d_out, int out_size, void* d_ws, size_t ws_size,
                              hipStream_t stream) {
  (void)in_sizes; (void)n_in; (void)out_size; (void)ws_size;
  const float* ins    = (const float*)d_in[0];
  const int*   resets = (const int*)  d_in[1];
  // d_in[2] = h0 (all zeros; chain starts bake h=0)
  const float* Wir = (const float*)d_in[3];
  const float* Wiz = (const float*)d_in[4];
  const float* Win = (const float*)d_in[5];
  const float* Whr = (const float*)d_in[6];
  const float* Whz = (const float*)d_in[7];
  const float* Whn = (const float*)d_in[8];
  const float* bir = (const float*)d_in[9];
  const float* biz = (const float*)d_in[10];
  const float* bin_ = (const float*)d_in[11];
  const float* bhn = (const float*)d_in[12];

  u16* wt = (u16*)d_ws;  // 192 slabs * 16KB = 3 MB

  prep_w<<<6144, 256, 0, stream>>>(Wir, Wiz, Win, Whr, Whz, Whn, wt);
  gru_chains<<<Bn, 1024, 0, stream>>>(ins, resets, wt, bir, biz, bin_, bhn, (float*)d_out);
}

// Round 13
// 1331.609 us; speedup vs baseline: 1.0303x; 1.0303x over previous
//
#include <hip/hip_runtime.h>

typedef unsigned short u16;
typedef unsigned int u32;
typedef unsigned long long u64;
typedef __attribute__((ext_vector_type(8))) short bf16x8;
typedef __attribute__((ext_vector_type(4))) float f32x4;
typedef __attribute__((ext_vector_type(4))) float fvec4;

#define Tn 512
#define Bn 256
#define Hn 512
#define SLOTS 32
#define SLABB 16384      // 16KB slab: [16 waves][4 kseg][16 col][16B]
#define NSLAB 192        // (kk*6+g)*2+half
#define RING 5           // 80KB LDS ring; issue-lag 4, steady vmcnt(3)

__device__ __forceinline__ u16 f2bf(float x){
  u32 u = __builtin_bit_cast(u32, x);
  u32 r = u + 0x7FFFu + ((u >> 16) & 1u);
  return (u16)(r >> 16);
}
__device__ __forceinline__ float bf2f(u16 x){
  return __builtin_bit_cast(float, ((u32)x) << 16);
}
__device__ __forceinline__ float sigmoid_f(float x){ return 1.0f/(1.0f + __expf(-x)); }
__device__ __forceinline__ float tanh_f(float x){ return 2.0f/(1.0f + __expf(-2.0f*x)) - 1.0f; }

__device__ __forceinline__ void dma16(const void* g, void* l) {
  __builtin_amdgcn_global_load_lds(
      (const __attribute__((address_space(1))) unsigned int*)g,
      (__attribute__((address_space(3))) unsigned int*)l,
      16, 0, 0);
}

// A-frag read from swizzled x/h LDS
__device__ __forceinline__ bf16x8 ldsA(const u16* buf, int m, int kk, int lane) {
  const int row = (m << 4) + (lane & 15);
  const int ke  = (kk << 5) + ((lane >> 4) << 3);
  const int byt = (row << 10) + ((ke << 1) ^ ((row & 7) << 4));
  return *(const bf16x8*)((const char*)buf + byt);
}

// Pack weights into slab order (R6's verified layout).
// Slab s = (kk*6+g)*2+half; within slab: e = wv*512 + kseg*128 + c*8 + j
//   = W_g[(kk*32 + kseg*8 + j)*512 + half*256 + wv*16 + c]
__global__ __launch_bounds__(256) void prep_w(
    const float* __restrict__ Wir, const float* __restrict__ Wiz, const float* __restrict__ Win,
    const float* __restrict__ Whr, const float* __restrict__ Whz, const float* __restrict__ Whn,
    u16* __restrict__ wt)
{
  int idx = blockIdx.x * 256 + threadIdx.x;   // 0 .. 6*512*512-1
  int within = idx & 8191;
  int slab = idx >> 13;
  int wv   = within >> 9;
  int r2   = within & 511;
  int kseg = r2 >> 7;
  int c    = (r2 >> 3) & 15;
  int j    = r2 & 7;
  int half = slab & 1;
  int gk = slab >> 1;
  int g  = gk % 6;
  int kk = gk / 6;
  int k = (kk << 5) + (kseg << 3) + j;
  int n = (half << 8) + (wv << 4) + c;
  const float* W;
  switch (g) {
    case 0: W = Wir; break; case 1: W = Wiz; break; case 2: W = Win; break;
    case 3: W = Whr; break; case 4: W = Whz; break; default: W = Whn; break;
  }
  wt[idx] = f2bf(W[k * Hn + n]);
}

// Phase body, NO drains/fences. MODE: 0 = phase-0 (no issue, vmcnt(3));
// 1 = steady (issue slab p+4 into prev buffer, vmcnt(3)); 2 = tail with
// explicit wait TW; 3 = last phase (no issue, no wait).
// Safety of no-lgkm-drain: the buffer overwritten (prevoff) was ds_read at
// phase p-1; that read completed before its MFMA issued (compiler's counted
// lgkmcnt on the register dep), and we are past that MFMA in program order.
#define PHASE_BODY(AXH0, AXH1, ACC, HALF, MODE, TW)                                  \
  do {                                                                               \
    bf16x8 bb = *(const bf16x8*)(wring + bufoff + brd_off);                          \
    ACC[HALF][0] = __builtin_amdgcn_mfma_f32_16x16x32_bf16(AXH0, bb, ACC[HALF][0], 0, 0, 0); \
    ACC[HALF][1] = __builtin_amdgcn_mfma_f32_16x16x32_bf16(AXH1, bb, ACC[HALF][1], 0, 0, 0); \
    if (MODE == 1) {                                                                 \
      dma16(pf, wring + prevoff + lds_wave_off);                                     \
      pf += SLABB;                                                                   \
      asm volatile("s_waitcnt vmcnt(3)" ::: "memory");                               \
    } else if (MODE == 0) {                                                          \
      asm volatile("s_waitcnt vmcnt(3)" ::: "memory");                               \
    } else if (MODE == 2) {                                                          \
      if (TW == 2)      asm volatile("s_waitcnt vmcnt(2)" ::: "memory");             \
      else if (TW == 1) asm volatile("s_waitcnt vmcnt(1)" ::: "memory");             \
      else              asm volatile("s_waitcnt vmcnt(0)" ::: "memory");             \
    }                                                                                \
    prevoff = bufoff;                                                                \
    bufoff = (bufoff == 4 * SLABB) ? 0 : bufoff + SLABB;                             \
  } while (0)

// One WG (1024 thr, 16 waves) per batch row; 5-slab wave-private LDS ring,
// single-slab phases, issue-lag 4, no lgkm drains, no sched fences.
__global__ __launch_bounds__(1024, 4) void gru_chains(
    const float* __restrict__ ins,      // [T,B,H] fp32
    const int*   __restrict__ resets,   // [T,B] int32 0/1
    const u16*   __restrict__ wt,       // [192] slabs of 16KB
    const float* __restrict__ bir, const float* __restrict__ biz,
    const float* __restrict__ bin_, const float* __restrict__ bhn,
    float* __restrict__ out)            // [T,B,H] fp32
{
  __shared__ __attribute__((aligned(16))) u16 x_lds[SLOTS * 512];    // 32KB swizzled
  __shared__ __attribute__((aligned(16))) u16 h_lds[SLOTS * 512];    // 32KB swizzled
  __shared__ __attribute__((aligned(16))) char wring[RING * SLABB];  // 80KB ring
  __shared__ u32 keys[512];
  __shared__ int slot_t[SLOTS];
  __shared__ int slot_end[SLOTS];
  __shared__ int slot_active[SLOTS];
  __shared__ int slot_fresh[SLOTS];
  __shared__ int wave_cnt[16];
  __shared__ int queue_head, n_chains, n_active;

  const int tid  = threadIdx.x;
  const int b    = blockIdx.x;
  const int wv   = tid >> 6;
  const int lane = tid & 63;

  // ---------------- chain extraction + LPT sort ----------------
  {
    u32* starts_tmp = (u32*)wring;   // wring unused during setup
    int t = tid;
    int isst = 0;
    if (t < Tn) isst = (t == 0) || (resets[t * Bn + b] != 0);
    u64 mask = __ballot(isst);
    int pos = __popcll(mask & ((1ull << lane) - 1ull));
    if (lane == 0) wave_cnt[wv] = __popcll(mask);
    __syncthreads();
    if (tid == 0) {
      int s = 0;
      for (int w = 0; w < 16; ++w) { int c = wave_cnt[w]; wave_cnt[w] = s; s += c; }
      n_chains = s;
      queue_head = SLOTS;
    }
    __syncthreads();
    if (isst) starts_tmp[wave_cnt[wv] + pos] = (u32)t;
    __syncthreads();
    const int nc = n_chains;
    if (tid < 512) {
      int i = tid;
      u32 key = 0;
      if (i < nc) {
        u32 st = starts_tmp[i];
        u32 en = (i + 1 < nc) ? starts_tmp[i + 1] : (u32)Tn;
        key = ((en - st) << 16) | st;
      }
      keys[i] = key;
    }
    for (int ks = 2; ks <= 512; ks <<= 1) {
      for (int j = ks >> 1; j > 0; j >>= 1) {
        __syncthreads();
        if (tid < 512) {
          int i = tid;
          int ix = i ^ j;
          if (ix > i) {
            u32 a = keys[i], c = keys[ix];
            bool desc = ((i & ks) == 0);
            bool sw = desc ? (a < c) : (a > c);
            if (sw) { keys[i] = c; keys[ix] = a; }
          }
        }
      }
    }
    __syncthreads();
    if (tid < SLOTS) {
      if (tid < nc) {
        u32 key = keys[tid];
        slot_t[tid]   = (int)(key & 0xFFFFu);
        slot_end[tid] = (int)((key & 0xFFFFu) + (key >> 16));
        slot_active[tid] = 1;
      } else {
        slot_active[tid] = 0; slot_t[tid] = 0; slot_end[tid] = 0;
      }
      slot_fresh[tid] = 0;
    }
    if (tid == 0) n_active = (nc < SLOTS) ? nc : SLOTS;
    for (int i = tid; i < SLOTS * 512 / 2; i += 1024) ((u32*)h_lds)[i] = 0;
    __syncthreads();
  }

  // ---- initial x stage: 2048 granules of 8 bf16, 2 per thread ----
  #pragma unroll
  for (int i = 0; i < 2; ++i) {
    const int g   = tid + (i << 10);
    const int row = g >> 6;
    const int k0  = (g & 63) << 3;
    const int act = slot_active[row];
    const int tc  = slot_t[row];
    fvec4 f0 = (fvec4){0.f, 0.f, 0.f, 0.f}, f1 = f0;
    if (act) {
      const fvec4* src = (const fvec4*)(ins + ((size_t)tc * Bn + b) * Hn + k0);
      f0 = __builtin_nontemporal_load(src);
      f1 = __builtin_nontemporal_load(src + 1);
    }
    uint4 pk;
    pk.x = (u32)f2bf(f0.x) | ((u32)f2bf(f0.y) << 16);
    pk.y = (u32)f2bf(f0.z) | ((u32)f2bf(f0.w) << 16);
    pk.z = (u32)f2bf(f1.x) | ((u32)f2bf(f1.y) << 16);
    pk.w = (u32)f2bf(f1.z) | ((u32)f2bf(f1.w) << 16);
    const int byt = (row << 10) + ((k0 << 1) ^ ((row & 7) << 4));
    *(uint4*)((char*)x_lds + byt) = pk;
  }
  __syncthreads();   // drains all counters; per-wave vmcnt bookkeeping clean

  // bias registers
  const int colw = (wv << 4) + (lane & 15);            // col within 256-half
  float b_r[2], b_z[2], b_n[2], b_h[2];
  #pragma unroll
  for (int half = 0; half < 2; ++half) {
    const int col = (half << 8) + colw;
    b_r[half] = bir[col]; b_z[half] = biz[col]; b_n[half] = bin_[col]; b_h[half] = bhn[col];
  }

  const u32 dm_lane_off  = (u32)((wv << 10) + (lane << 4));  // per-lane src off in slab
  const u32 lds_wave_off = (u32)(wv << 10);                  // wave-uniform LDS dest slice
  const int brd_off      = (wv << 10) + ((lane >> 4) << 8) + ((lane & 15) << 4);

  // ---------------- microstep loop ----------------
  for (;;) {
    f32x4 accR[2][2], accZ[2][2], accXN[2][2], accHN[2][2];   // [half][mfrag]
    #pragma unroll
    for (int hh = 0; hh < 2; ++hh)
      #pragma unroll
      for (int m = 0; m < 2; ++m) {
        accR[hh][m] = (f32x4){0.f, 0.f, 0.f, 0.f};
        accZ[hh][m] = accR[hh][m]; accXN[hh][m] = accR[hh][m]; accHN[hh][m] = accR[hh][m];
      }

    // prologue: issue slabs 0..4, wait slab0 (4 newest still pending)
    const char* pf = (const char*)wt + dm_lane_off;
    {
      #pragma unroll
      for (int s = 0; s < RING; ++s) {
        dma16(pf, wring + s * SLABB + lds_wave_off);
        pf += SLABB;
      }
      asm volatile("s_waitcnt vmcnt(4)" ::: "memory");
    }

    u32 bufoff = 0, prevoff = 0;
    // kk = 0 peeled: phase 0 = MODE 0 (no issue), phases 1..11 = MODE 1
    {
      const int kk = 0;
      bf16x8 ax0, ax1, ah0, ah1;
      #pragma unroll
      for (int g = 0; g < 6; ++g) {
        if (g == 0) { ax0 = ldsA(x_lds, 0, kk, lane); ax1 = ldsA(x_lds, 1, kk, lane); }
        if (g == 3) { ah0 = ldsA(h_lds, 0, kk, lane); ah1 = ldsA(h_lds, 1, kk, lane); }
        bf16x8 a0 = (g < 3) ? ax0 : ah0;
        bf16x8 a1 = (g < 3) ? ax1 : ah1;
        #pragma unroll
        for (int half = 0; half < 2; ++half) {
          const int mode = (g == 0 && half == 0) ? 0 : 1;
          if (g == 0 || g == 3)      PHASE_BODY(a0, a1, accR,  half, mode, -1);
          else if (g == 1 || g == 4) PHASE_BODY(a0, a1, accZ,  half, mode, -1);
          else if (g == 2)           PHASE_BODY(a0, a1, accXN, half, mode, -1);
          else                       PHASE_BODY(a0, a1, accHN, half, mode, -1);
        }
      }
    }
    // kk = 1..14 rolled, all MODE 1
    for (int kk = 1; kk < 15; ++kk) {
      bf16x8 ax0, ax1, ah0, ah1;
      #pragma unroll
      for (int g = 0; g < 6; ++g) {
        if (g == 0) { ax0 = ldsA(x_lds, 0, kk, lane); ax1 = ldsA(x_lds, 1, kk, lane); }
        if (g == 3) { ah0 = ldsA(h_lds, 0, kk, lane); ah1 = ldsA(h_lds, 1, kk, lane); }
        bf16x8 a0 = (g < 3) ? ax0 : ah0;
        bf16x8 a1 = (g < 3) ? ax1 : ah1;
        #pragma unroll
        for (int half = 0; half < 2; ++half) {
          if (g == 0 || g == 3)      PHASE_BODY(a0, a1, accR,  half, 1, -1);
          else if (g == 1 || g == 4) PHASE_BODY(a0, a1, accZ,  half, 1, -1);
          else if (g == 2)           PHASE_BODY(a0, a1, accXN, half, 1, -1);
          else                       PHASE_BODY(a0, a1, accHN, half, 1, -1);
        }
      }
    }
    // kk = 15 peeled: phases 180..187 issue (p+4 <= 191); 188..190 tail waits
    // (TW = 190-p); phase 191 = MODE 3 (nothing)
    {
      const int kk = 15;
      bf16x8 ax0, ax1, ah0, ah1;
      #pragma unroll
      for (int g = 0; g < 6; ++g) {
        if (g == 0) { ax0 = ldsA(x_lds, 0, kk, lane); ax1 = ldsA(x_lds, 1, kk, lane); }
        if (g == 3) { ah0 = ldsA(h_lds, 0, kk, lane); ah1 = ldsA(h_lds, 1, kk, lane); }
        bf16x8 a0 = (g < 3) ? ax0 : ah0;
        bf16x8 a1 = (g < 3) ? ax1 : ah1;
        #pragma unroll
        for (int half = 0; half < 2; ++half) {
          const int p = 180 + g * 2 + half;
          const int mode = (p <= 187) ? 1 : ((p <= 190) ? 2 : 3);
          const int tw = 190 - p;                      // 2,1,0 for p=188..190
          if (g == 0 || g == 3)      PHASE_BODY(a0, a1, accR,  half, mode, tw);
          else if (g == 1 || g == 4) PHASE_BODY(a0, a1, accZ,  half, mode, tw);
          else if (g == 2)           PHASE_BODY(a0, a1, accXN, half, mode, tw);
          else                       PHASE_BODY(a0, a1, accHN, half, mode, tw);
        }
      }
    }

    __syncthreads();   // all waves done reading x_lds/h_lds

    // ---- epilogue: gates, h update (in place), y store ----
    #pragma unroll
    for (int half = 0; half < 2; ++half) {
      const int col = (half << 8) + colw;
      const float bi_r = b_r[half], bi_z = b_z[half], bi_n = b_n[half], bh_n = b_h[half];
      #pragma unroll
      for (int m = 0; m < 2; ++m) {
        #pragma unroll
        for (int i = 0; i < 4; ++i) {
          const int slot = (m << 4) + ((lane >> 4) << 2) + i;
          float rr = sigmoid_f(accR[half][m][i] + bi_r);
          float zz = sigmoid_f(accZ[half][m][i] + bi_z);
          const int hbyt = (slot << 10) + ((col << 1) ^ ((slot & 7) << 4));
          float hold = bf2f(*(const u16*)((const char*)h_lds + hbyt));
          float nn = tanh_f(accXN[half][m][i] + bi_n + rr * (accHN[half][m][i] + bh_n));
          float hnew = (1.0f - zz) * nn + zz * hold;
          *(u16*)((char*)h_lds + hbyt) = f2bf(hnew);   // (slot,col) owned by this thread
          if (slot_active[slot]) {
            __builtin_nontemporal_store(hnew, out + ((size_t)slot_t[slot] * Bn + b) * Hn + col);
          }
        }
      }
    }
    __syncthreads();

    // ---- advance slots / repack from queue ----
    if (tid < SLOTS) {
      const int s = tid;
      int fresh = 0;
      if (slot_active[s]) {
        int nt = slot_t[s] + 1;
        if (nt >= slot_end[s]) {
          int idx = atomicAdd(&queue_head, 1);
          if (idx < n_chains) {
            u32 key = keys[idx];
            slot_t[s]   = (int)(key & 0xFFFFu);
            slot_end[s] = (int)((key & 0xFFFFu) + (key >> 16));
            fresh = 1;
          } else {
            slot_active[s] = 0;
            atomicSub(&n_active, 1);
            fresh = 1;
          }
        } else {
          slot_t[s] = nt;
        }
      }
      slot_fresh[s] = fresh;
    }
    __syncthreads();

    // ---- stage next x + zero h rows of fresh/inactive slots ----
    #pragma unroll
    for (int i = 0; i < 2; ++i) {
      const int g   = tid + (i << 10);
      const int row = g >> 6;
      const int k0  = (g & 63) << 3;
      const int act = slot_active[row];
      const int tc  = slot_t[row];
      const int kill = slot_fresh[row] | (act == 0);
      const int sbyt = (row << 10) + ((k0 << 1) ^ ((row & 7) << 4));
      if (kill) *(uint4*)((char*)h_lds + sbyt) = (uint4){0, 0, 0, 0};
      fvec4 f0 = (fvec4){0.f, 0.f, 0.f, 0.f}, f1 = f0;
      if (act) {
        const fvec4* src = (const fvec4*)(ins + ((size_t)tc * Bn + b) * Hn + k0);
        f0 = __builtin_nontemporal_load(src);
        f1 = __builtin_nontemporal_load(src + 1);
      }
      uint4 pk;
      pk.x = (u32)f2bf(f0.x) | ((u32)f2bf(f0.y) << 16);
      pk.y = (u32)f2bf(f0.z) | ((u32)f2bf(f0.w) << 16);
      pk.z = (u32)f2bf(f1.x) | ((u32)f2bf(f1.y) << 16);
      pk.w = (u32)f2bf(f1.z) | ((u32)f2bf(f1.w) << 16);
      *(uint4*)((char*)x_lds + sbyt) = pk;
    }
    __syncthreads();    // drains all vmem counters before next prologue

    if (n_active <= 0) break;
  }
}

extern "C" void kernel_launch(void* const* d_in, const int* in_sizes, int n_in,
                              void* d_out, int out_size, void* d_ws, size_t ws_size,
                              hipStream_t stream) {
  (void)in_sizes; (void)n_in; (void)out_size; (void)ws_size;
  const float* ins    = (const float*)d_in[0];
  const int*   resets = (const int*)  d_in[1];
  // d_in[2] = h0 (all zeros; chain starts bake h=0)
  const float* Wir = (const float*)d_in[3];
  const float* Wiz = (const float*)d_in[4];
  const float* Win = (const float*)d_in[5];
  const float* Whr = (const float*)d_in[6];
  const float* Whz = (const float*)d_in[7];
  const float* Whn = (const float*)d_in[8];
  const float* bir = (const float*)d_in[9];
  const float* biz = (const float*)d_in[10];
  const float* bin_ = (const float*)d_in[11];
  const float* bhn = (const float*)d_in[12];

  u16* wt = (u16*)d_ws;  // 192 slabs * 16KB = 3 MB

  prep_w<<<6144, 256, 0, stream>>>(Wir, Wiz, Win, Whr, Whz, Whn, wt);
  gru_chains<<<Bn, 1024, 0, stream>>>(ins, resets, wt, bir, biz, bin_, bhn, (float*)d_out);
}

// Round 14
// 797.096 us; speedup vs baseline: 1.7212x; 1.6706x over previous
//
#include <hip/hip_runtime.h>

typedef unsigned short u16;
typedef unsigned int u32;
typedef unsigned long long u64;
typedef __attribute__((ext_vector_type(8))) short bf16x8;
typedef __attribute__((ext_vector_type(4))) float f32x4;
typedef __attribute__((ext_vector_type(4))) float fvec4;

#define Tn 512
#define Bn 256
#define Hn 512
#define SLOTS 32
#define SLABB 16384      // 16KB slab: [16 waves][4 kseg][16 col][16B]
#define NSLAB 192        // (kk*6+g)*2+half

__device__ __forceinline__ u16 f2bf(float x){
  u32 u = __builtin_bit_cast(u32, x);
  u32 r = u + 0x7FFFu + ((u >> 16) & 1u);
  return (u16)(r >> 16);
}
__device__ __forceinline__ float bf2f(u16 x){
  return __builtin_bit_cast(float, ((u32)x) << 16);
}
__device__ __forceinline__ float sigmoid_f(float x){ return 1.0f/(1.0f + __expf(-x)); }
__device__ __forceinline__ float tanh_f(float x){ return 2.0f/(1.0f + __expf(-2.0f*x)) - 1.0f; }

__device__ __forceinline__ void dma16(const void* g, void* l) {
  __builtin_amdgcn_global_load_lds(
      (const __attribute__((address_space(1))) unsigned int*)g,
      (__attribute__((address_space(3))) unsigned int*)l,
      16, 0, 0);
}

// A-frag read from swizzled x/h LDS
__device__ __forceinline__ bf16x8 ldsA(const u16* buf, int m, int kk, int lane) {
  const int row = (m << 4) + (lane & 15);
  const int ke  = (kk << 5) + ((lane >> 4) << 3);
  const int byt = (row << 10) + ((ke << 1) ^ ((row & 7) << 4));
  return *(const bf16x8*)((const char*)buf + byt);
}

// MFMA quad: ACC[half][mfrag]; uses a0,a1,b0,b1 from scope
#define MF4(ACC) do { \
  ACC[0][0] = __builtin_amdgcn_mfma_f32_16x16x32_bf16(a0, b0, ACC[0][0], 0, 0, 0); \
  ACC[0][1] = __builtin_amdgcn_mfma_f32_16x16x32_bf16(a1, b0, ACC[0][1], 0, 0, 0); \
  ACC[1][0] = __builtin_amdgcn_mfma_f32_16x16x32_bf16(a0, b1, ACC[1][0], 0, 0, 0); \
  ACC[1][1] = __builtin_amdgcn_mfma_f32_16x16x32_bf16(a1, b1, ACC[1][1], 0, 0, 0); \
} while (0)

// Pack weights into slab order (R6's verified layout).
// Slab s = (kk*6+g)*2+half; within slab: e = wv*512 + kseg*128 + c*8 + j
//   = W_g[(kk*32 + kseg*8 + j)*512 + half*256 + wv*16 + c]
__global__ __launch_bounds__(256) void prep_w(
    const float* __restrict__ Wir, const float* __restrict__ Wiz, const float* __restrict__ Win,
    const float* __restrict__ Whr, const float* __restrict__ Whz, const float* __restrict__ Whn,
    u16* __restrict__ wt)
{
  int idx = blockIdx.x * 256 + threadIdx.x;   // 0 .. 6*512*512-1
  int within = idx & 8191;
  int slab = idx >> 13;
  int wv   = within >> 9;
  int r2   = within & 511;
  int kseg = r2 >> 7;
  int c    = (r2 >> 3) & 15;
  int j    = r2 & 7;
  int half = slab & 1;
  int gk = slab >> 1;
  int g  = gk % 6;
  int kk = gk / 6;
  int k = (kk << 5) + (kseg << 3) + j;
  int n = (half << 8) + (wv << 4) + c;
  const float* W;
  switch (g) {
    case 0: W = Wir; break; case 1: W = Wiz; break; case 2: W = Win; break;
    case 3: W = Whr; break; case 4: W = Whz; break; default: W = Whn; break;
  }
  wt[idx] = f2bf(W[k * Hn + n]);
}

// One WG (1024 thr, 16 waves) per batch row. R6 pair-phase pipeline with the
// inter-phase overhead removed: 2 barriers/microstep (advance runs during
// phases into parity-flipped slot arrays; h-zeroing folded into epilogue),
// prologue DMAs for step s+1 issued at start of s's epilogue region (latency
// hidden; end barrier drains so phase-0 vmcnt accounting starts clean), and
// no runtime lgkmcnt drain in the phase body (R13-verified safe; one
// sched_barrier(0) anti-hoist fence before the DMAs).
__global__ __launch_bounds__(1024, 4) void gru_chains(
    const float* __restrict__ ins,      // [T,B,H] fp32
    const int*   __restrict__ resets,   // [T,B] int32 0/1
    const u16*   __restrict__ wt,       // [192] slabs of 16KB
    const float* __restrict__ bir, const float* __restrict__ biz,
    const float* __restrict__ bin_, const float* __restrict__ bhn,
    float* __restrict__ out)            // [T,B,H] fp32
{
  __shared__ __attribute__((aligned(16))) u16 x_lds[SLOTS * 512];   // 32KB swizzled
  __shared__ __attribute__((aligned(16))) u16 h_lds[SLOTS * 512];   // 32KB swizzled
  __shared__ __attribute__((aligned(16))) char wring[4 * SLABB];    // 64KB ring
  __shared__ u32 keys[512];
  __shared__ int slot_t[2][SLOTS];
  __shared__ int slot_end[2][SLOTS];
  __shared__ int slot_active[2][SLOTS];
  __shared__ int slot_fresh[2][SLOTS];
  __shared__ int n_act[2];
  __shared__ int wave_cnt[16];
  __shared__ int queue_head, n_chains;

  const int tid  = threadIdx.x;
  const int b    = blockIdx.x;
  const int wv   = tid >> 6;
  const int lane = tid & 63;

  // ---------------- chain extraction + LPT sort ----------------
  {
    u32* starts_tmp = (u32*)wring;   // wring unused during setup
    int t = tid;
    int isst = 0;
    if (t < Tn) isst = (t == 0) || (resets[t * Bn + b] != 0);
    u64 mask = __ballot(isst);
    int pos = __popcll(mask & ((1ull << lane) - 1ull));
    if (lane == 0) wave_cnt[wv] = __popcll(mask);
    __syncthreads();
    if (tid == 0) {
      int s = 0;
      for (int w = 0; w < 16; ++w) { int c = wave_cnt[w]; wave_cnt[w] = s; s += c; }
      n_chains = s;
      queue_head = SLOTS;
    }
    __syncthreads();
    if (isst) starts_tmp[wave_cnt[wv] + pos] = (u32)t;
    __syncthreads();
    const int nc = n_chains;
    if (tid < 512) {
      int i = tid;
      u32 key = 0;
      if (i < nc) {
        u32 st = starts_tmp[i];
        u32 en = (i + 1 < nc) ? starts_tmp[i + 1] : (u32)Tn;
        key = ((en - st) << 16) | st;
      }
      keys[i] = key;
    }
    for (int ks = 2; ks <= 512; ks <<= 1) {
      for (int j = ks >> 1; j > 0; j >>= 1) {
        __syncthreads();
        if (tid < 512) {
          int i = tid;
          int ix = i ^ j;
          if (ix > i) {
            u32 a = keys[i], c = keys[ix];
            bool desc = ((i & ks) == 0);
            bool sw = desc ? (a < c) : (a > c);
            if (sw) { keys[i] = c; keys[ix] = a; }
          }
        }
      }
    }
    __syncthreads();
    if (tid < SLOTS) {
      if (tid < nc) {
        u32 key = keys[tid];
        slot_t[0][tid]   = (int)(key & 0xFFFFu);
        slot_end[0][tid] = (int)((key & 0xFFFFu) + (key >> 16));
        slot_active[0][tid] = 1;
      } else {
        slot_active[0][tid] = 0; slot_t[0][tid] = 0; slot_end[0][tid] = 0;
      }
      slot_fresh[0][tid] = 0;
    }
    if (tid == 0) n_act[0] = (nc < SLOTS) ? nc : SLOTS;
    for (int i = tid; i < SLOTS * 512 / 2; i += 1024) ((u32*)h_lds)[i] = 0;
    __syncthreads();
  }

  const int colw = (wv << 4) + (lane & 15);            // col within 256-half
  float b_r[2], b_z[2], b_n[2], b_h[2];
  #pragma unroll
  for (int half = 0; half < 2; ++half) {
    const int col = (half << 8) + colw;
    b_r[half] = bir[col]; b_z[half] = biz[col]; b_n[half] = bin_[col]; b_h[half] = bhn[col];
  }

  const u32 dm_lane_off  = (u32)((wv << 10) + (lane << 4));  // per-lane src off in slab
  const u32 lds_wave_off = (u32)(wv << 10);                  // wave-uniform LDS dest slice
  const int brd_off      = (wv << 10) + ((lane >> 4) << 8) + ((lane & 15) << 4);

  // ---- initial x stage (parity 0) + initial prologue issue ----
  #pragma unroll
  for (int i = 0; i < 2; ++i) {
    const int g   = tid + (i << 10);
    const int row = g >> 6;
    const int k0  = (g & 63) << 3;
    const int act = slot_active[0][row];
    const int tc  = slot_t[0][row];
    fvec4 f0 = (fvec4){0.f, 0.f, 0.f, 0.f}, f1 = f0;
    if (act) {
      const fvec4* src = (const fvec4*)(ins + ((size_t)tc * Bn + b) * Hn + k0);
      f0 = __builtin_nontemporal_load(src);
      f1 = __builtin_nontemporal_load(src + 1);
    }
    uint4 pk;
    pk.x = (u32)f2bf(f0.x) | ((u32)f2bf(f0.y) << 16);
    pk.y = (u32)f2bf(f0.z) | ((u32)f2bf(f0.w) << 16);
    pk.z = (u32)f2bf(f1.x) | ((u32)f2bf(f1.y) << 16);
    pk.w = (u32)f2bf(f1.z) | ((u32)f2bf(f1.w) << 16);
    const int byt = (row << 10) + ((k0 << 1) ^ ((row & 7) << 4));
    *(uint4*)((char*)x_lds + byt) = pk;
  }
  {
    const char* wsrc = (const char*)wt + dm_lane_off;
    #pragma unroll
    for (int s = 0; s < 4; ++s)
      dma16(wsrc + (size_t)s * SLABB, wring + s * SLABB + lds_wave_off);
    __builtin_amdgcn_sched_barrier(0);
  }
  __syncthreads();   // drains everything; ring bufs 0-3 valid; vmcnt clean

  int cp = 0;        // current slot-array parity

  // ---------------- microstep loop ----------------
  for (;;) {
    const int np = cp ^ 1;

    // ---- slot advance for s+1, by wave 0, concurrent with phases ----
    if (tid < SLOTS) {
      const int s = tid;
      int act = slot_active[cp][s];
      int t   = slot_t[cp][s];
      int en  = slot_end[cp][s];
      int fresh = 0;
      if (act) {
        int nt2 = t + 1;
        if (nt2 >= en) {
          int idx = atomicAdd(&queue_head, 1);
          if (idx < n_chains) {
            u32 key = keys[idx];
            t = (int)(key & 0xFFFFu); en = t + (int)(key >> 16); fresh = 1;
          } else {
            act = 0; fresh = 1;
          }
        } else {
          t = nt2;
        }
      }
      slot_t[np][s] = t; slot_end[np][s] = en;
      slot_active[np][s] = act; slot_fresh[np][s] = fresh;
      u64 am = __ballot(act != 0);
      if (tid == 0) n_act[np] = __popcll(am);
    }

    // ---- accumulators ----
    f32x4 accR[2][2], accZ[2][2], accXN[2][2], accHN[2][2];   // [half][mfrag]
    #pragma unroll
    for (int hh = 0; hh < 2; ++hh)
      #pragma unroll
      for (int m = 0; m < 2; ++m) {
        accR[hh][m] = (f32x4){0.f, 0.f, 0.f, 0.f};
        accZ[hh][m] = accR[hh][m]; accXN[hh][m] = accR[hh][m]; accHN[hh][m] = accR[hh][m];
      }

    // ---- 96 pair-phases; bufs 0-3 pre-loaded (prologue of previous region) ----
    for (int kk = 0; kk < 16; ++kk) {
      bf16x8 ax0, ax1, ah0, ah1;
      #pragma unroll
      for (int g = 0; g < 6; ++g) {
        if (g == 0) { ax0 = ldsA(x_lds, 0, kk, lane); ax1 = ldsA(x_lds, 1, kk, lane); }
        if (g == 3) { ah0 = ldsA(h_lds, 0, kk, lane); ah1 = ldsA(h_lds, 1, kk, lane); }
        const int ph  = kk * 6 + g;
        const int rb0 = (ph & 1) << 1;                 // pair bufs {rb0, rb0+1}
        const char* bbp = wring + rb0 * SLABB + brd_off;
        bf16x8 b0 = *(const bf16x8*)bbp;               // half 0
        bf16x8 b1 = *(const bf16x8*)(bbp + SLABB);     // half 1
        bf16x8 a0 = (g < 3) ? ax0 : ah0;
        bf16x8 a1 = (g < 3) ? ax1 : ah1;
        if (g == 0 || g == 3)      MF4(accR);
        else if (g == 1 || g == 4) MF4(accZ);
        else if (g == 2)           MF4(accXN);
        else                       MF4(accHN);
        // anti-hoist fence: DMAs below must not move above the ds_reads/MFMAs
        __builtin_amdgcn_sched_barrier(0);
        const int s0 = (ph << 1) + 4;
        if (s0 < NSLAB) {
          const char* wsrc = (const char*)wt + (size_t)s0 * SLABB + dm_lane_off;
          dma16(wsrc,         wring + rb0 * SLABB + lds_wave_off);
          dma16(wsrc + SLABB, wring + (rb0 + 1) * SLABB + lds_wave_off);
          asm volatile("s_waitcnt vmcnt(2)" ::: "memory");
        } else {
          asm volatile("s_waitcnt vmcnt(0)" ::: "memory");
        }
      }
    }

    __syncthreads();   // bar A: all waves done reading x_lds/h_lds; advance visible

    // ---- prologue DMAs for NEXT microstep (hidden under epilogue + x-stage) ----
    {
      const char* wsrc = (const char*)wt + dm_lane_off;
      #pragma unroll
      for (int s = 0; s < 4; ++s)
        dma16(wsrc + (size_t)s * SLABB, wring + s * SLABB + lds_wave_off);
      __builtin_amdgcn_sched_barrier(0);
    }

    // ---- epilogue: gates, h update (zeroing fresh/inactive-next), y store ----
    #pragma unroll
    for (int half = 0; half < 2; ++half) {
      const int col = (half << 8) + colw;
      const float bi_r = b_r[half], bi_z = b_z[half], bi_n = b_n[half], bh_n = b_h[half];
      #pragma unroll
      for (int m = 0; m < 2; ++m) {
        #pragma unroll
        for (int i = 0; i < 4; ++i) {
          const int slot = (m << 4) + ((lane >> 4) << 2) + i;
          float rr = sigmoid_f(accR[half][m][i] + bi_r);
          float zz = sigmoid_f(accZ[half][m][i] + bi_z);
          const int hbyt = (slot << 10) + ((col << 1) ^ ((slot & 7) << 4));
          float hold = bf2f(*(const u16*)((const char*)h_lds + hbyt));
          float nn = tanh_f(accXN[half][m][i] + bi_n + rr * (accHN[half][m][i] + bh_n));
          float hnew = (1.0f - zz) * nn + zz * hold;
          const int kill = slot_fresh[np][slot] | (slot_active[np][slot] == 0);
          *(u16*)((char*)h_lds + hbyt) = f2bf(kill ? 0.0f : hnew);
          if (slot_active[cp][slot]) {
            __builtin_nontemporal_store(hnew,
                out + ((size_t)slot_t[cp][slot] * Bn + b) * Hn + col);
          }
        }
      }
    }

    // ---- stage next x (parity np) — same barrier region as epilogue ----
    #pragma unroll
    for (int i = 0; i < 2; ++i) {
      const int g   = tid + (i << 10);
      const int row = g >> 6;
      const int k0  = (g & 63) << 3;
      const int act = slot_active[np][row];
      const int tc  = slot_t[np][row];
      fvec4 f0 = (fvec4){0.f, 0.f, 0.f, 0.f}, f1 = f0;
      if (act) {
        const fvec4* src = (const fvec4*)(ins + ((size_t)tc * Bn + b) * Hn + k0);
        f0 = __builtin_nontemporal_load(src);
        f1 = __builtin_nontemporal_load(src + 1);
      }
      uint4 pk;
      pk.x = (u32)f2bf(f0.x) | ((u32)f2bf(f0.y) << 16);
      pk.y = (u32)f2bf(f0.z) | ((u32)f2bf(f0.w) << 16);
      pk.z = (u32)f2bf(f1.x) | ((u32)f2bf(f1.y) << 16);
      pk.w = (u32)f2bf(f1.z) | ((u32)f2bf(f1.w) << 16);
      const int byt = (row << 10) + ((k0 << 1) ^ ((row & 7) << 4));
      *(uint4*)((char*)x_lds + byt) = pk;
    }

    __syncthreads();   // bar B: drains all (incl. prologue DMAs, long landed)

    if (n_act[np] <= 0) break;
    cp = np;
  }
}

extern "C" void kernel_launch(void* const* d_in, const int* in_sizes, int n_in,
                              void* d_out, int out_size, void* d_ws, size_t ws_size,
                              hipStream_t stream) {
  (void)in_sizes; (void)n_in; (void)out_size; (void)ws_size;
  const float* ins    = (const float*)d_in[0];
  const int*   resets = (const int*)  d_in[1];
  // d_in[2] = h0 (all zeros; chain starts bake h=0)
  const float* Wir = (const float*)d_in[3];
  const float* Wiz = (const float*)d_in[4];
  const float* Win = (const float*)d_in[5];
  const float* Whr = (const float*)d_in[6];
  const float* Whz = (const float*)d_in[7];
  const float* Whn = (const float*)d_in[8];
  const float* bir = (const float*)d_in[9];
  const float* biz = (const float*)d_in[10];
  const float* bin_ = (const float*)d_in[11];
  const float* bhn = (const float*)d_in[12];

  u16* wt = (u16*)d_ws;  // 192 slabs * 16KB = 3 MB

  prep_w<<<6144, 256, 0, stream>>>(Wir, Wiz, Win, Whr, Whz, Whn, wt);
  gru_chains<<<Bn, 1024, 0, stream>>>(ins, resets, wt, bir, biz, bin_, bhn, (float*)d_out);
}